// Round 5
// baseline (228.789 us; speedup 1.0000x reference)
//
#include <hip/hip_runtime.h>
#include <math.h>

#define Bb 256
#define Nn 256
#define Dd 512
#define Cc 1024
#define KC 8          // split-K chunks in logits
#define KD (Dd / KC)  // 64 d per chunk
#define PR 32         // rows per prep block
#define PSTR 516      // padded LDS row stride (floats)

__device__ __forceinline__ float waveReduceSum(float v) {
    #pragma unroll
    for (int off = 32; off > 0; off >>= 1)
        v += __shfl_xor(v, off, 64);
    return v;
}
__device__ __forceinline__ float waveReduceMax(float v) {
    #pragma unroll
    for (int off = 32; off > 0; off >>= 1)
        v = fmaxf(v, __shfl_xor(v, off, 64));
    return v;
}

// P: fused text prep. grid = C/PR = 32 blocks, 256 threads.
// txt_t[d][c] = txt[c][d] / max(||txt[c]||, eps)
__global__ void k_prep(const float* __restrict__ txt, float* __restrict__ txt_t) {
    __shared__ float tile[PR * PSTR];   // ~66 KB
    __shared__ float invs[PR];
    const int c0 = blockIdx.x * PR;
    const int tid = threadIdx.x;
    // phase 1: coalesced float4 loads
    #pragma unroll
    for (int i = tid; i < PR * 128; i += 256) {
        const int r = i >> 7, c4 = i & 127;
        const float4 v = *(const float4*)(txt + (size_t)(c0 + r) * Dd + c4 * 4);
        *(float4*)&tile[r * PSTR + c4 * 4] = v;
    }
    __syncthreads();
    // phase 2: per-row sumsq, 8 threads per row (32 rows x 8 = 256)
    {
        const int r = tid >> 3, k = tid & 7;
        float s = 0.f;
        #pragma unroll
        for (int i = 0; i < 64; ++i) {
            const float x = tile[r * PSTR + i * 8 + k];
            s = fmaf(x, x, s);
        }
        s += __shfl_xor(s, 1, 64);
        s += __shfl_xor(s, 2, 64);
        s += __shfl_xor(s, 4, 64);
        if (k == 0) invs[r] = 1.0f / fmaxf(sqrtf(s), 1e-12f);
    }
    __syncthreads();
    // phase 3: scaled transpose out; 32 consecutive c per store group (128B/half-wave)
    {
        const int c = tid & 31;
        const int d0 = tid >> 5;   // 0..7
        const float inv = invs[c];
        #pragma unroll
        for (int d = d0; d < Dd; d += 8)
            txt_t[(size_t)d * Cc + c0 + c] = tile[c * PSTR + d] * inv;
    }
}

// B: fused simgt+softmax+q, half-batch per block with online softmax.
// grid = 2*B blocks, 512 threads (8 waves x 16 rows = 128 rows = N/2).
// Outputs per (b,half): qp[.][d] unnormalized, mS[.] = (m, S).
__global__ void __launch_bounds__(512) k_attn_q(const float* __restrict__ toks,
                                                const float* __restrict__ txt,
                                                const int* __restrict__ pid,
                                                const float* __restrict__ log_attn_tau,
                                                float* __restrict__ qp,
                                                float2* __restrict__ mS) {
    const int b = blockIdx.x >> 1;
    const int half = blockIdx.x & 1;
    const int tid = threadIdx.x;
    const int wv = tid >> 6;     // 0..7
    const int lane = tid & 63;
    __shared__ float xg[Dd];
    __shared__ float qpart_s[8][Dd];   // 16 KB
    __shared__ float ms[8], Ss[8], ssw[8];
    const int g = pid[b];
    // load raw txt[g] row; block-reduce its sumsq
    {
        const float x = txt[(size_t)g * Dd + tid];
        xg[tid] = x;
        float s = waveReduceSum(x * x);
        if (lane == 0) ssw[wv] = s;
    }
    __syncthreads();
    float ssg = 0.f;
    #pragma unroll
    for (int w = 0; w < 8; ++w) ssg += ssw[w];
    const float invg = 1.0f / fmaxf(sqrtf(ssg), 1e-12f);

    float at = expf(log_attn_tau[0]);
    at = fminf(fmaxf(at, 0.01f), 1.0f);
    const float iat = 1.0f / at;

    const float4 xg0 = *(const float4*)&xg[lane * 8];
    const float4 xg1 = *(const float4*)&xg[lane * 8 + 4];

    float m = -INFINITY, S = 0.0f;
    float qa[8] = {0.f, 0.f, 0.f, 0.f, 0.f, 0.f, 0.f, 0.f};

    const float* base = toks + ((size_t)b * Nn + half * 128 + wv * 16) * Dd + lane * 8;
    // prefetch depth 2
    float4 c0a = *(const float4*)base;
    float4 c0b = *(const float4*)(base + 4);
    float4 c1a = *(const float4*)(base + Dd);
    float4 c1b = *(const float4*)(base + Dd + 4);
    #pragma unroll 4
    for (int r = 0; r < 16; ++r) {
        float4 na, nb;
        if (r < 14) {
            const float* p = base + (size_t)(r + 2) * Dd;
            na = *(const float4*)p;
            nb = *(const float4*)(p + 4);
        }
        float dot = c0a.x*xg0.x + c0a.y*xg0.y + c0a.z*xg0.z + c0a.w*xg0.w
                  + c0b.x*xg1.x + c0b.y*xg1.y + c0b.z*xg1.z + c0b.w*xg1.w;
        float ss  = c0a.x*c0a.x + c0a.y*c0a.y + c0a.z*c0a.z + c0a.w*c0a.w
                  + c0b.x*c0b.x + c0b.y*c0b.y + c0b.z*c0b.z + c0b.w*c0b.w;
        dot = waveReduceSum(dot);
        ss = waveReduceSum(ss);
        const float inv = 1.0f / fmaxf(sqrtf(ss), 1e-12f);
        const float s = dot * inv * invg;    // lane-invariant -> wave-uniform branch
        if (s > m) {
            const float sc = expf((m - s) * iat);   // first iter: exp(-inf)=0
            S = S * sc + 1.0f;
            qa[0] = qa[0]*sc + inv*c0a.x; qa[1] = qa[1]*sc + inv*c0a.y;
            qa[2] = qa[2]*sc + inv*c0a.z; qa[3] = qa[3]*sc + inv*c0a.w;
            qa[4] = qa[4]*sc + inv*c0b.x; qa[5] = qa[5]*sc + inv*c0b.y;
            qa[6] = qa[6]*sc + inv*c0b.z; qa[7] = qa[7]*sc + inv*c0b.w;
            m = s;
        } else {
            const float e = expf((s - m) * iat);
            S += e;
            const float w = e * inv;
            qa[0] = fmaf(w, c0a.x, qa[0]); qa[1] = fmaf(w, c0a.y, qa[1]);
            qa[2] = fmaf(w, c0a.z, qa[2]); qa[3] = fmaf(w, c0a.w, qa[3]);
            qa[4] = fmaf(w, c0b.x, qa[4]); qa[5] = fmaf(w, c0b.y, qa[5]);
            qa[6] = fmaf(w, c0b.z, qa[6]); qa[7] = fmaf(w, c0b.w, qa[7]);
        }
        c0a = c1a; c0b = c1b; c1a = na; c1b = nb;
    }
    #pragma unroll
    for (int j = 0; j < 8; ++j) qpart_s[wv][lane * 8 + j] = qa[j];
    if (lane == 0) { ms[wv] = m; Ss[wv] = S; }
    __syncthreads();
    {
        float M = -INFINITY;
        #pragma unroll
        for (int w = 0; w < 8; ++w) M = fmaxf(M, ms[w]);
        float Stot = 0.f, acc = 0.f;
        #pragma unroll
        for (int w = 0; w < 8; ++w) {
            const float sc = expf((ms[w] - M) * iat);
            Stot = fmaf(Ss[w], sc, Stot);
            acc = fmaf(qpart_s[w][tid], sc, acc);
        }
        qp[((size_t)b * 2 + half) * Dd + tid] = acc;   // unnormalized
        if (tid == 0) mS[b * 2 + half] = make_float2(M, Stot);
    }
}

// E: split-K logits partials; combines the two attn halves on the fly.
// grid = (B/4, KC), 256 threads.
__global__ void k_logits(const float* __restrict__ qp, const float2* __restrict__ mS,
                         const float* __restrict__ log_attn_tau,
                         const float* __restrict__ txt_t, float* __restrict__ part) {
    const int b0 = blockIdx.x * 4;
    const int kc = blockIdx.y;
    const int d0 = kc * KD;
    const int t = threadIdx.x;
    __shared__ float qs[4][KD];
    __shared__ float A0s[4], A1s[4], RSs[4];
    if (t < 4) {
        float at = expf(log_attn_tau[0]);
        at = fminf(fmaxf(at, 0.01f), 1.0f);
        const float iat = 1.0f / at;
        const float2 h0 = mS[(b0 + t) * 2 + 0];
        const float2 h1 = mS[(b0 + t) * 2 + 1];
        const float M = fmaxf(h0.x, h1.x);
        const float a0 = expf((h0.x - M) * iat);
        const float a1 = expf((h1.x - M) * iat);
        A0s[t] = a0; A1s[t] = a1;
        RSs[t] = 1.0f / (h0.y * a0 + h1.y * a1);
    }
    __syncthreads();
    {
        const int j = t >> 6, d = t & 63;
        const float v0 = qp[((size_t)(b0 + j) * 2 + 0) * Dd + d0 + d];
        const float v1 = qp[((size_t)(b0 + j) * 2 + 1) * Dd + d0 + d];
        qs[j][d] = (v0 * A0s[j] + v1 * A1s[j]) * RSs[j];
    }
    __syncthreads();
    const float4* xt = (const float4*)txt_t;   // [D][C/4]
    float4 a0 = {0,0,0,0}, a1 = {0,0,0,0}, a2 = {0,0,0,0}, a3 = {0,0,0,0};
    #pragma unroll 4
    for (int d = 0; d < KD; d += 4) {
        const float4 q0 = *(const float4*)&qs[0][d];
        const float4 q1 = *(const float4*)&qs[1][d];
        const float4 q2 = *(const float4*)&qs[2][d];
        const float4 q3 = *(const float4*)&qs[3][d];
        const float4 x0 = xt[(size_t)(d0 + d + 0) * (Cc / 4) + t];
        const float4 x1 = xt[(size_t)(d0 + d + 1) * (Cc / 4) + t];
        const float4 x2 = xt[(size_t)(d0 + d + 2) * (Cc / 4) + t];
        const float4 x3 = xt[(size_t)(d0 + d + 3) * (Cc / 4) + t];
        a0.x = fmaf(q0.x,x0.x,a0.x); a0.y = fmaf(q0.x,x0.y,a0.y); a0.z = fmaf(q0.x,x0.z,a0.z); a0.w = fmaf(q0.x,x0.w,a0.w);
        a0.x = fmaf(q0.y,x1.x,a0.x); a0.y = fmaf(q0.y,x1.y,a0.y); a0.z = fmaf(q0.y,x1.z,a0.z); a0.w = fmaf(q0.y,x1.w,a0.w);
        a0.x = fmaf(q0.z,x2.x,a0.x); a0.y = fmaf(q0.z,x2.y,a0.y); a0.z = fmaf(q0.z,x2.z,a0.z); a0.w = fmaf(q0.z,x2.w,a0.w);
        a0.x = fmaf(q0.w,x3.x,a0.x); a0.y = fmaf(q0.w,x3.y,a0.y); a0.z = fmaf(q0.w,x3.z,a0.z); a0.w = fmaf(q0.w,x3.w,a0.w);
        a1.x = fmaf(q1.x,x0.x,a1.x); a1.y = fmaf(q1.x,x0.y,a1.y); a1.z = fmaf(q1.x,x0.z,a1.z); a1.w = fmaf(q1.x,x0.w,a1.w);
        a1.x = fmaf(q1.y,x1.x,a1.x); a1.y = fmaf(q1.y,x1.y,a1.y); a1.z = fmaf(q1.y,x1.z,a1.z); a1.w = fmaf(q1.y,x1.w,a1.w);
        a1.x = fmaf(q1.z,x2.x,a1.x); a1.y = fmaf(q1.z,x2.y,a1.y); a1.z = fmaf(q1.z,x2.z,a1.z); a1.w = fmaf(q1.z,x2.w,a1.w);
        a1.x = fmaf(q1.w,x3.x,a1.x); a1.y = fmaf(q1.w,x3.y,a1.y); a1.z = fmaf(q1.w,x3.z,a1.z); a1.w = fmaf(q1.w,x3.w,a1.w);
        a2.x = fmaf(q2.x,x0.x,a2.x); a2.y = fmaf(q2.x,x0.y,a2.y); a2.z = fmaf(q2.x,x0.z,a2.z); a2.w = fmaf(q2.x,x0.w,a2.w);
        a2.x = fmaf(q2.y,x1.x,a2.x); a2.y = fmaf(q2.y,x1.y,a2.y); a2.z = fmaf(q2.y,x1.z,a2.z); a2.w = fmaf(q2.y,x1.w,a2.w);
        a2.x = fmaf(q2.z,x2.x,a2.x); a2.y = fmaf(q2.z,x2.y,a2.y); a2.z = fmaf(q2.z,x2.z,a2.z); a2.w = fmaf(q2.z,x2.w,a2.w);
        a2.x = fmaf(q2.w,x3.x,a2.x); a2.y = fmaf(q2.w,x3.y,a2.y); a2.z = fmaf(q2.w,x3.z,a2.z); a2.w = fmaf(q2.w,x3.w,a2.w);
        a3.x = fmaf(q3.x,x0.x,a3.x); a3.y = fmaf(q3.x,x0.y,a3.y); a3.z = fmaf(q3.x,x0.z,a3.z); a3.w = fmaf(q3.x,x0.w,a3.w);
        a3.x = fmaf(q3.y,x1.x,a3.x); a3.y = fmaf(q3.y,x1.y,a3.y); a3.z = fmaf(q3.y,x1.z,a3.z); a3.w = fmaf(q3.y,x1.w,a3.w);
        a3.x = fmaf(q3.z,x2.x,a3.x); a3.y = fmaf(q3.z,x2.y,a3.y); a3.z = fmaf(q3.z,x2.z,a3.z); a3.w = fmaf(q3.z,x2.w,a3.w);
        a3.x = fmaf(q3.w,x3.x,a3.x); a3.y = fmaf(q3.w,x3.y,a3.y); a3.z = fmaf(q3.w,x3.z,a3.z); a3.w = fmaf(q3.w,x3.w,a3.w);
    }
    float* pb = part + ((size_t)kc * Bb + b0) * Cc;
    ((float4*)(pb + 0 * Cc))[t] = a0;
    ((float4*)(pb + 1 * Cc))[t] = a1;
    ((float4*)(pb + 2 * Cc))[t] = a2;
    ((float4*)(pb + 3 * Cc))[t] = a3;
}

// E2: sum K-partials, 1/tau, LSE + NLL, atomic mean accumulate. grid = B, 256 thr.
__global__ void k_lse(const float* __restrict__ part, const int* __restrict__ pid,
                      const float* __restrict__ log_tau, float* __restrict__ out) {
    const int b = blockIdx.x;
    const int t = threadIdx.x;   // 4 c's each
    float4 l = {0,0,0,0};
    #pragma unroll
    for (int kc = 0; kc < KC; ++kc) {
        const float4 p = ((const float4*)(part + ((size_t)kc * Bb + b) * Cc))[t];
        l.x += p.x; l.y += p.y; l.z += p.z; l.w += p.w;
    }
    float tau = expf(log_tau[0]);
    tau = fminf(fmaxf(tau, 0.01f), 1.0f);
    const float itau = 1.0f / tau;
    l.x *= itau; l.y *= itau; l.z *= itau; l.w *= itau;

    const int g = pid[b];
    __shared__ float redm[4], reds[4], sgt;
    if ((g >> 2) == t) {
        const float v[4] = {l.x, l.y, l.z, l.w};
        sgt = v[g & 3];
    }
    float m = fmaxf(fmaxf(l.x, l.y), fmaxf(l.z, l.w));
    m = waveReduceMax(m);
    if ((t & 63) == 0) redm[t >> 6] = m;
    __syncthreads();
    m = fmaxf(fmaxf(redm[0], redm[1]), fmaxf(redm[2], redm[3]));
    float e = expf(l.x - m) + expf(l.y - m) + expf(l.z - m) + expf(l.w - m);
    e = waveReduceSum(e);
    if ((t & 63) == 0) reds[t >> 6] = e;
    __syncthreads();
    if (t == 0) {
        const float S = reds[0] + reds[1] + reds[2] + reds[3];
        const float nll = m + logf(S) - sgt;
        atomicAdd(out, nll * (1.0f / (float)Bb));
    }
}

extern "C" void kernel_launch(void* const* d_in, const int* in_sizes, int n_in,
                              void* d_out, int out_size, void* d_ws, size_t ws_size,
                              hipStream_t stream) {
    const float* toks = (const float*)d_in[0];     // [B,N,D] fp32
    const float* txt = (const float*)d_in[1];      // [C,D] fp32
    const float* log_tau = (const float*)d_in[2];
    const float* log_attn_tau = (const float*)d_in[3];
    const int* pid = (const int*)d_in[4];          // [B] int32
    float* out = (float*)d_out;

    float* ws = (float*)d_ws;
    float* txt_t = ws;                             // D*C (normalized transpose)
    float* qp    = txt_t + (size_t)Dd * Cc;        // B*2*D (unnormalized half-q)
    float2* mS   = (float2*)(qp + (size_t)Bb * 2 * Dd);  // B*2
    float* part  = (float*)(mS + Bb * 2);          // KC*B*C

    hipMemsetAsync(out, 0, sizeof(float), stream);   // d_out is poisoned each replay
    k_attn_q<<<Bb * 2, 512, 0, stream>>>(toks, txt, pid, log_attn_tau, qp, mS);
    k_prep<<<Cc / PR, 256, 0, stream>>>(txt, txt_t);
    k_logits<<<dim3(Bb / 4, KC), 256, 0, stream>>>(qp, mS, log_attn_tau, txt_t, part);
    k_lse<<<Bb, 256, 0, stream>>>(part, pid, log_tau, out);
}

// Round 6
// 221.948 us; speedup vs baseline: 1.0308x; 1.0308x over previous
//
#include <hip/hip_runtime.h>
#include <math.h>

#define Bb 256
#define Nn 256
#define Dd 512
#define Cc 1024
#define KC 16         // split-K chunks in logits
#define KD (Dd / KC)  // 32 d per chunk
#define BT 8          // b-tile in logits
#define PR 16         // rows per prep block
#define PSTR 516      // padded LDS row stride (floats)

__device__ __forceinline__ float waveReduceSum(float v) {
    #pragma unroll
    for (int off = 32; off > 0; off >>= 1)
        v += __shfl_xor(v, off, 64);
    return v;
}
__device__ __forceinline__ float waveReduceMax(float v) {
    #pragma unroll
    for (int off = 32; off > 0; off >>= 1)
        v = fmaxf(v, __shfl_xor(v, off, 64));
    return v;
}

// P: fused text prep. grid = C/PR = 64 blocks, 256 threads.
// txt_t[d][c] = txt[c][d] * invc[c],  invc[c] = 1/max(||txt[c]||, eps)
__global__ void k_prep(const float* __restrict__ txt, float* __restrict__ txt_t,
                       float* __restrict__ invc) {
    __shared__ float tile[PR * PSTR];   // ~33 KB
    __shared__ float invs[PR];
    const int c0 = blockIdx.x * PR;
    const int tid = threadIdx.x;
    #pragma unroll
    for (int i = tid; i < PR * 128; i += 256) {
        const int r = i >> 7, c4 = i & 127;
        const float4 v = *(const float4*)(txt + (size_t)(c0 + r) * Dd + c4 * 4);
        *(float4*)&tile[r * PSTR + c4 * 4] = v;
    }
    __syncthreads();
    {
        const int r = tid >> 4, k = tid & 15;
        float s = 0.f;
        #pragma unroll
        for (int i = 0; i < 32; ++i) {
            const float x = tile[r * PSTR + i * 16 + k];
            s = fmaf(x, x, s);
        }
        s += __shfl_xor(s, 1, 64);
        s += __shfl_xor(s, 2, 64);
        s += __shfl_xor(s, 4, 64);
        s += __shfl_xor(s, 8, 64);
        if (k == 0) {
            const float inv = 1.0f / fmaxf(sqrtf(s), 1e-12f);
            invs[r] = inv;
            invc[c0 + r] = inv;
        }
    }
    __syncthreads();
    {
        const int c = tid & 15;
        const int d0 = tid >> 4;   // 0..15
        const float inv = invs[c];
        #pragma unroll
        for (int d = d0; d < Dd; d += 16)
            txt_t[(size_t)d * Cc + c0 + c] = tile[c * PSTR + d] * inv;
    }
}

// B (fused simgt+softmax+qpart): ONE pass over tokens with online softmax.
// grid = B blocks, 1024 threads (16 waves, 16 rows each).
__global__ void __launch_bounds__(1024) k_attn_q(const float* __restrict__ toks,
                                                 const float* __restrict__ txt,
                                                 const float* __restrict__ invc,
                                                 const int* __restrict__ pid,
                                                 const float* __restrict__ log_attn_tau,
                                                 float* __restrict__ q) {
    const int b = blockIdx.x;
    const int tid = threadIdx.x;
    const int wv = tid >> 6;     // 0..15
    const int lane = tid & 63;
    __shared__ float xg[Dd];
    __shared__ float qpart_s[16][Dd];   // 32 KB
    __shared__ float ms[16], Ss[16];
    const int g = pid[b];
    if (tid < Dd) xg[tid] = txt[(size_t)g * Dd + tid] * invc[g];
    __syncthreads();
    float at = expf(log_attn_tau[0]);
    at = fminf(fmaxf(at, 0.01f), 1.0f);
    const float iat = 1.0f / at;

    const float4 xg0 = *(const float4*)&xg[lane * 8];
    const float4 xg1 = *(const float4*)&xg[lane * 8 + 4];

    float m = -INFINITY, S = 0.0f;
    float qa[8] = {0.f, 0.f, 0.f, 0.f, 0.f, 0.f, 0.f, 0.f};

    const float* base = toks + ((size_t)b * Nn + wv * 16) * Dd + lane * 8;
    float4 t0 = *(const float4*)base;
    float4 t1 = *(const float4*)(base + 4);
    #pragma unroll 4
    for (int r = 0; r < 16; ++r) {
        float4 n0, n1;
        if (r < 15) {   // prefetch next row
            const float* p = base + (size_t)(r + 1) * Dd;
            n0 = *(const float4*)p;
            n1 = *(const float4*)(p + 4);
        }
        float dot = t0.x*xg0.x + t0.y*xg0.y + t0.z*xg0.z + t0.w*xg0.w
                  + t1.x*xg1.x + t1.y*xg1.y + t1.z*xg1.z + t1.w*xg1.w;
        float ss  = t0.x*t0.x + t0.y*t0.y + t0.z*t0.z + t0.w*t0.w
                  + t1.x*t1.x + t1.y*t1.y + t1.z*t1.z + t1.w*t1.w;
        dot = waveReduceSum(dot);
        ss = waveReduceSum(ss);
        const float inv = 1.0f / fmaxf(sqrtf(ss), 1e-12f);
        const float s = dot * inv;     // lane-invariant -> wave-uniform branch
        if (s > m) {
            const float sc = expf((m - s) * iat);   // first iter: exp(-inf)=0
            S = S * sc + 1.0f;
            qa[0] = qa[0]*sc + inv*t0.x; qa[1] = qa[1]*sc + inv*t0.y;
            qa[2] = qa[2]*sc + inv*t0.z; qa[3] = qa[3]*sc + inv*t0.w;
            qa[4] = qa[4]*sc + inv*t1.x; qa[5] = qa[5]*sc + inv*t1.y;
            qa[6] = qa[6]*sc + inv*t1.z; qa[7] = qa[7]*sc + inv*t1.w;
            m = s;
        } else {
            const float e = expf((s - m) * iat);
            S += e;
            const float w = e * inv;
            qa[0] = fmaf(w, t0.x, qa[0]); qa[1] = fmaf(w, t0.y, qa[1]);
            qa[2] = fmaf(w, t0.z, qa[2]); qa[3] = fmaf(w, t0.w, qa[3]);
            qa[4] = fmaf(w, t1.x, qa[4]); qa[5] = fmaf(w, t1.y, qa[5]);
            qa[6] = fmaf(w, t1.z, qa[6]); qa[7] = fmaf(w, t1.w, qa[7]);
        }
        t0 = n0; t1 = n1;
    }
    #pragma unroll
    for (int j = 0; j < 8; ++j) qpart_s[wv][lane * 8 + j] = qa[j];
    if (lane == 0) { ms[wv] = m; Ss[wv] = S; }
    __syncthreads();
    if (tid < Dd) {
        float M = -INFINITY;
        #pragma unroll
        for (int w = 0; w < 16; ++w) M = fmaxf(M, ms[w]);
        float Stot = 0.f, acc = 0.f;
        #pragma unroll
        for (int w = 0; w < 16; ++w) {
            const float sc = expf((ms[w] - M) * iat);
            Stot = fmaf(Ss[w], sc, Stot);
            acc = fmaf(qpart_s[w][tid], sc, acc);
        }
        q[(size_t)b * Dd + tid] = acc / Stot;
    }
}

// E: split-K logits partials, b-tile 8. grid = (B/BT, KC) = (32,16), 256 threads.
// part[kc][b][c] = sum_{d in chunk} q[b][d] * txt_t[d][c]
__global__ void k_logits(const float* __restrict__ q, const float* __restrict__ txt_t,
                         float* __restrict__ part) {
    const int b0 = blockIdx.x * BT;
    const int kc = blockIdx.y;
    const int d0 = kc * KD;
    const int t = threadIdx.x;     // one float4 of c per thread (1024 c / 4 = 256)
    __shared__ float qs[BT][KD];
    {
        const int j = t >> 5, d = t & 31;   // 8 x 32 = 256
        qs[j][d] = q[(size_t)(b0 + j) * Dd + d0 + d];
    }
    __syncthreads();
    const float4* xt = (const float4*)txt_t;   // [D][C/4]
    float4 acc[BT];
    #pragma unroll
    for (int j = 0; j < BT; ++j) acc[j] = make_float4(0.f, 0.f, 0.f, 0.f);
    #pragma unroll 4
    for (int d = 0; d < KD; ++d) {
        const float4 x = xt[(size_t)(d0 + d) * (Cc / 4) + t];
        #pragma unroll
        for (int j = 0; j < BT; ++j) {
            const float qv = qs[j][d];     // LDS broadcast (same addr across wave)
            acc[j].x = fmaf(qv, x.x, acc[j].x);
            acc[j].y = fmaf(qv, x.y, acc[j].y);
            acc[j].z = fmaf(qv, x.z, acc[j].z);
            acc[j].w = fmaf(qv, x.w, acc[j].w);
        }
    }
    float* pb = part + ((size_t)kc * Bb + b0) * Cc;
    #pragma unroll
    for (int j = 0; j < BT; ++j)
        ((float4*)(pb + (size_t)j * Cc))[t] = acc[j];
}

// E2: sum K-partials, 1/tau, LSE + NLL, atomic mean accumulate. grid = B, 256 thr.
__global__ void k_lse(const float* __restrict__ part, const int* __restrict__ pid,
                      const float* __restrict__ log_tau, float* __restrict__ out) {
    const int b = blockIdx.x;
    const int t = threadIdx.x;   // 4 c's each
    float4 l = {0,0,0,0};
    #pragma unroll
    for (int kc = 0; kc < KC; ++kc) {
        const float4 p = ((const float4*)(part + ((size_t)kc * Bb + b) * Cc))[t];
        l.x += p.x; l.y += p.y; l.z += p.z; l.w += p.w;
    }
    float tau = expf(log_tau[0]);
    tau = fminf(fmaxf(tau, 0.01f), 1.0f);
    const float itau = 1.0f / tau;
    l.x *= itau; l.y *= itau; l.z *= itau; l.w *= itau;

    const int g = pid[b];
    __shared__ float redm[4], reds[4], sgt;
    if ((g >> 2) == t) {
        const float v[4] = {l.x, l.y, l.z, l.w};
        sgt = v[g & 3];
    }
    float m = fmaxf(fmaxf(l.x, l.y), fmaxf(l.z, l.w));
    m = waveReduceMax(m);
    if ((t & 63) == 0) redm[t >> 6] = m;
    __syncthreads();
    m = fmaxf(fmaxf(redm[0], redm[1]), fmaxf(redm[2], redm[3]));
    float e = expf(l.x - m) + expf(l.y - m) + expf(l.z - m) + expf(l.w - m);
    e = waveReduceSum(e);
    if ((t & 63) == 0) reds[t >> 6] = e;
    __syncthreads();
    if (t == 0) {
        const float S = reds[0] + reds[1] + reds[2] + reds[3];
        const float nll = m + logf(S) - sgt;
        atomicAdd(out, nll * (1.0f / (float)Bb));
    }
}

extern "C" void kernel_launch(void* const* d_in, const int* in_sizes, int n_in,
                              void* d_out, int out_size, void* d_ws, size_t ws_size,
                              hipStream_t stream) {
    const float* toks = (const float*)d_in[0];     // [B,N,D] fp32
    const float* txt = (const float*)d_in[1];      // [C,D] fp32
    const float* log_tau = (const float*)d_in[2];
    const float* log_attn_tau = (const float*)d_in[3];
    const int* pid = (const int*)d_in[4];          // [B] int32
    float* out = (float*)d_out;

    float* ws = (float*)d_ws;
    float* txt_t = ws;                             // D*C (normalized transpose)
    float* invc  = txt_t + (size_t)Dd * Cc;        // C
    float* q     = invc + Cc;                      // B*D
    float* part  = q + (size_t)Bb * Dd;            // KC*B*C

    hipMemsetAsync(out, 0, sizeof(float), stream);   // d_out is poisoned each replay
    k_prep<<<Cc / PR, 256, 0, stream>>>(txt, txt_t, invc);
    k_attn_q<<<Bb, 1024, 0, stream>>>(toks, txt, invc, pid, log_attn_tau, q);
    k_logits<<<dim3(Bb / BT, KC), 256, 0, stream>>>(q, txt_t, part);
    k_lse<<<Bb, 256, 0, stream>>>(part, pid, log_tau, out);
}